// Round 1
// baseline (5462.454 us; speedup 1.0000x reference)
//
#include <hip/hip_runtime.h>

#define N_NODES 10000
#define N_EDGES 640000

// ---------------------------------------------------------------------------
// Copy kernel: seed aggregation buffer with x (so scatter-add yields x + agg)
// ---------------------------------------------------------------------------
__global__ __launch_bounds__(256) void copy_f4(const float4* __restrict__ in,
                                               float4* __restrict__ out, int n4) {
    int i = blockIdx.x * blockDim.x + threadIdx.x;
    if (i < n4) out[i] = in[i];
}

// ---------------------------------------------------------------------------
// Scatter-add: out[dst[e]][c] += x[src[e]][c]   (out pre-seeded with x)
// One thread per (edge, 4-channel group). C4 = channels/4.
// ---------------------------------------------------------------------------
template <int C4>
__global__ __launch_bounds__(256) void scatter_add(const float* __restrict__ x,
                                                   const int* __restrict__ src,
                                                   const int* __restrict__ dst,
                                                   float* __restrict__ out,
                                                   int nEdges) {
    long long t = (long long)blockIdx.x * blockDim.x + threadIdx.x;
    int e = (int)(t / C4);
    int c = (int)(t % C4);
    if (e >= nEdges) return;
    int s = src[e];
    int d = dst[e];
    float4 v = *(const float4*)(x + ((size_t)s * C4 + c) * 4);
    float* o = out + ((size_t)d * C4 + c) * 4;
    unsafeAtomicAdd(o + 0, v.x);
    unsafeAtomicAdd(o + 1, v.y);
    unsafeAtomicAdd(o + 2, v.z);
    unsafeAtomicAdd(o + 3, v.w);
}

// ---------------------------------------------------------------------------
// FP32 register-tiled GEMM: C[M,N] = A[M,K] @ W[K,N] + bias, optional ReLU,
// optional dual-store (C2 gets the same values — seeds next scatter buffer).
// BM=BN=64, BK=16, 256 threads, 4x4 acc per thread.
// ---------------------------------------------------------------------------
template <bool RELU, bool DUAL>
__global__ __launch_bounds__(256) void gemm_bias(const float* __restrict__ A,
                                                 const float* __restrict__ W,
                                                 const float* __restrict__ bias,
                                                 float* __restrict__ C,
                                                 float* __restrict__ C2,
                                                 int M, int K, int N) {
    const int BM = 64, BN = 64, BK = 16;
    __shared__ float As[BK][BM + 4];  // stored transposed: As[k][m]
    __shared__ float Bs[BK][BN + 4];  // Bs[k][n]

    int tid = threadIdx.x;
    int bm = blockIdx.x * BM;
    int bn = blockIdx.y * BN;
    int ty = tid >> 4;        // 0..15
    int tx = tid & 15;        // 0..15

    // A tile load mapping: one float4 per thread
    int arow = tid >> 2;           // 0..63
    int acol = (tid & 3) * 4;      // 0,4,8,12
    // B tile load mapping
    int brow = tid >> 4;           // 0..15
    int bcol = (tid & 15) * 4;     // 0..60

    float acc[4][4] = {};

    for (int k0 = 0; k0 < K; k0 += BK) {
        float4 av = make_float4(0.f, 0.f, 0.f, 0.f);
        int gm = bm + arow;
        if (gm < M) av = *(const float4*)(A + (size_t)gm * K + k0 + acol);
        As[acol + 0][arow] = av.x;
        As[acol + 1][arow] = av.y;
        As[acol + 2][arow] = av.z;
        As[acol + 3][arow] = av.w;

        float4 bv = *(const float4*)(W + (size_t)(k0 + brow) * N + bn + bcol);
        *(float4*)&Bs[brow][bcol] = bv;

        __syncthreads();
#pragma unroll
        for (int kk = 0; kk < BK; ++kk) {
            float4 a = *(const float4*)&As[kk][ty * 4];
            float4 b = *(const float4*)&Bs[kk][tx * 4];
            float aa[4] = {a.x, a.y, a.z, a.w};
            float bb[4] = {b.x, b.y, b.z, b.w};
#pragma unroll
            for (int i = 0; i < 4; ++i)
#pragma unroll
                for (int j = 0; j < 4; ++j)
                    acc[i][j] = fmaf(aa[i], bb[j], acc[i][j]);
        }
        __syncthreads();
    }

    float4 bsv = *(const float4*)(bias + bn + tx * 4);
    float bb[4] = {bsv.x, bsv.y, bsv.z, bsv.w};
#pragma unroll
    for (int i = 0; i < 4; ++i) {
        int gm = bm + ty * 4 + i;
        if (gm >= M) break;
        float4 o;
        float* po = (float*)&o;
#pragma unroll
        for (int j = 0; j < 4; ++j) {
            float v = acc[i][j] + bb[j];
            if (RELU) v = fmaxf(v, 0.f);
            po[j] = v;
        }
        *(float4*)(C + (size_t)gm * N + bn + tx * 4) = o;
        if (DUAL) *(float4*)(C2 + (size_t)gm * N + bn + tx * 4) = o;
    }
}

// ---------------------------------------------------------------------------
extern "C" void kernel_launch(void* const* d_in, const int* in_sizes, int n_in,
                              void* d_out, int out_size, void* d_ws, size_t ws_size,
                              hipStream_t stream) {
    const float* x   = (const float*)d_in[0];
    const int*   ei  = (const int*)d_in[1];
    const int*   src = ei;
    const int*   dst = ei + N_EDGES;
    const float* W0a = (const float*)d_in[2];
    const float* b0a = (const float*)d_in[3];
    const float* W0b = (const float*)d_in[4];
    const float* b0b = (const float*)d_in[5];
    const float* W1a = (const float*)d_in[6];
    const float* b1a = (const float*)d_in[7];
    const float* W1b = (const float*)d_in[8];
    const float* b1b = (const float*)d_in[9];
    const float* W2a = (const float*)d_in[10];
    const float* b2a = (const float*)d_in[11];
    const float* W2b = (const float*)d_in[12];
    const float* b2b = (const float*)d_in[13];
    float* out = (float*)d_out;

    const size_t BUF = (size_t)N_NODES * 256 * sizeof(float);  // 10.24 MB
    char* ws = (char*)d_ws;
    float* B0 = (float*)(ws);             // aggregation buffer (x + agg)
    float* B1 = (float*)(ws + BUF);       // MLP hidden
    float* B2 = (float*)(ws + 2 * BUF);   // layer output (scatter source)

    dim3 gemmGrid((N_NODES + 63) / 64, 256 / 64);
    dim3 gemmBlk(256);

    // ---- Layer 0 (C_in = 128) ----
    {
        int n4 = N_NODES * 128 / 4;
        copy_f4<<<(n4 + 255) / 256, 256, 0, stream>>>((const float4*)x, (float4*)B0, n4);
        long long total = (long long)N_EDGES * 32;
        scatter_add<32><<<(int)((total + 255) / 256), 256, 0, stream>>>(x, src, dst, B0, N_EDGES);
        gemm_bias<true, false><<<gemmGrid, gemmBlk, 0, stream>>>(B0, W0a, b0a, B1, nullptr, N_NODES, 128, 256);
        gemm_bias<true, true><<<gemmGrid, gemmBlk, 0, stream>>>(B1, W0b, b0b, B2, B0, N_NODES, 256, 256);
    }
    // ---- Layer 1 (C = 256) ----
    {
        long long total = (long long)N_EDGES * 64;
        scatter_add<64><<<(int)((total + 255) / 256), 256, 0, stream>>>(B2, src, dst, B0, N_EDGES);
        gemm_bias<true, false><<<gemmGrid, gemmBlk, 0, stream>>>(B0, W1a, b1a, B1, nullptr, N_NODES, 256, 256);
        gemm_bias<true, true><<<gemmGrid, gemmBlk, 0, stream>>>(B1, W1b, b1b, B2, B0, N_NODES, 256, 256);
    }
    // ---- Layer 2 (C = 256, no final ReLU) ----
    {
        long long total = (long long)N_EDGES * 64;
        scatter_add<64><<<(int)((total + 255) / 256), 256, 0, stream>>>(B2, src, dst, B0, N_EDGES);
        gemm_bias<true, false><<<gemmGrid, gemmBlk, 0, stream>>>(B0, W2a, b2a, B1, nullptr, N_NODES, 256, 256);
        gemm_bias<false, false><<<gemmGrid, gemmBlk, 0, stream>>>(B1, W2b, b2b, out, nullptr, N_NODES, 256, 256);
    }
}

// Round 2
// 419.249 us; speedup vs baseline: 13.0291x; 13.0291x over previous
//
#include <hip/hip_runtime.h>

#define N_NODES 10000
#define N_EDGES 640000

// ---------------------------------------------------------------------------
// CSR build: histogram of dst -> exclusive scan -> atomic fill of column list
// ---------------------------------------------------------------------------
__global__ __launch_bounds__(256) void hist_kernel(const int* __restrict__ dst,
                                                   int* __restrict__ cnt) {
    int e = blockIdx.x * blockDim.x + threadIdx.x;
    if (e < N_EDGES) atomicAdd(&cnt[dst[e]], 1);
}

__global__ __launch_bounds__(256) void scan_kernel(const int* __restrict__ cnt,
                                                   int* __restrict__ rowptr,
                                                   int* __restrict__ cursor) {
    __shared__ int partial[256];
    const int CH = 40;  // 256*40 >= 10000
    int t = threadIdx.x;
    int beg = t * CH, end = min(beg + CH, N_NODES);
    int s = 0;
    for (int i = beg; i < end; ++i) s += cnt[i];
    partial[t] = s;
    __syncthreads();
    // Hillis-Steele inclusive scan over 256 partials
    for (int off = 1; off < 256; off <<= 1) {
        int v = partial[t];
        int add = (t >= off) ? partial[t - off] : 0;
        __syncthreads();
        partial[t] = v + add;
        __syncthreads();
    }
    int run = (t == 0) ? 0 : partial[t - 1];
    for (int i = beg; i < end; ++i) {
        rowptr[i] = run;
        cursor[i] = run;
        run += cnt[i];
    }
    if (t == 255) rowptr[N_NODES] = run;  // = N_EDGES
}

__global__ __launch_bounds__(256) void fill_kernel(const int* __restrict__ src,
                                                   const int* __restrict__ dst,
                                                   int* __restrict__ cursor,
                                                   int* __restrict__ col) {
    int e = blockIdx.x * blockDim.x + threadIdx.x;
    if (e < N_EDGES) {
        int pos = atomicAdd(&cursor[dst[e]], 1);
        col[pos] = src[e];
    }
}

// ---------------------------------------------------------------------------
// Gather aggregation: out[n] = x[n] + sum_{j in row(n)} x[col[j]]
// One wave (64 lanes) per node. C=256 -> float4/lane, C=128 -> float2/lane.
// ---------------------------------------------------------------------------
__device__ inline float4 add4(float4 a, float4 b) {
    return make_float4(a.x + b.x, a.y + b.y, a.z + b.z, a.w + b.w);
}
__device__ inline float2 add2(float2 a, float2 b) {
    return make_float2(a.x + b.x, a.y + b.y);
}

__global__ __launch_bounds__(256) void gather_agg256(const float* __restrict__ x,
                                                     const int* __restrict__ rowptr,
                                                     const int* __restrict__ col,
                                                     float* __restrict__ out) {
    int wid = (blockIdx.x * 256 + threadIdx.x) >> 6;  // node id
    int lane = threadIdx.x & 63;
    if (wid >= N_NODES) return;
    const float4* xr = (const float4*)x;  // 64 float4 per row
    float4 acc = xr[(size_t)wid * 64 + lane];  // seed with self (eps=0)
    int beg = rowptr[wid], end = rowptr[wid + 1];
    int j = beg;
    for (; j + 4 <= end; j += 4) {
        int s0 = col[j], s1 = col[j + 1], s2 = col[j + 2], s3 = col[j + 3];
        float4 v0 = xr[(size_t)s0 * 64 + lane];
        float4 v1 = xr[(size_t)s1 * 64 + lane];
        float4 v2 = xr[(size_t)s2 * 64 + lane];
        float4 v3 = xr[(size_t)s3 * 64 + lane];
        acc = add4(acc, add4(add4(v0, v1), add4(v2, v3)));
    }
    for (; j < end; ++j) acc = add4(acc, xr[(size_t)col[j] * 64 + lane]);
    ((float4*)out)[(size_t)wid * 64 + lane] = acc;
}

__global__ __launch_bounds__(256) void gather_agg128(const float* __restrict__ x,
                                                     const int* __restrict__ rowptr,
                                                     const int* __restrict__ col,
                                                     float* __restrict__ out) {
    int wid = (blockIdx.x * 256 + threadIdx.x) >> 6;
    int lane = threadIdx.x & 63;
    if (wid >= N_NODES) return;
    const float2* xr = (const float2*)x;  // 64 float2 per row
    float2 acc = xr[(size_t)wid * 64 + lane];
    int beg = rowptr[wid], end = rowptr[wid + 1];
    int j = beg;
    for (; j + 4 <= end; j += 4) {
        int s0 = col[j], s1 = col[j + 1], s2 = col[j + 2], s3 = col[j + 3];
        float2 v0 = xr[(size_t)s0 * 64 + lane];
        float2 v1 = xr[(size_t)s1 * 64 + lane];
        float2 v2 = xr[(size_t)s2 * 64 + lane];
        float2 v3 = xr[(size_t)s3 * 64 + lane];
        acc = add2(acc, add2(add2(v0, v1), add2(v2, v3)));
    }
    for (; j < end; ++j) acc = add2(acc, xr[(size_t)col[j] * 64 + lane]);
    ((float2*)out)[(size_t)wid * 64 + lane] = acc;
}

// ---------------------------------------------------------------------------
// FP32 register-tiled GEMM: C[M,N] = A[M,K] @ W[K,N] + bias, optional ReLU.
// BM=BN=64, BK=16, 256 threads, 4x4 acc per thread.
// ---------------------------------------------------------------------------
template <bool RELU>
__global__ __launch_bounds__(256) void gemm_bias(const float* __restrict__ A,
                                                 const float* __restrict__ W,
                                                 const float* __restrict__ bias,
                                                 float* __restrict__ C,
                                                 int M, int K, int N) {
    const int BM = 64, BN = 64, BK = 16;
    __shared__ float As[BK][BM + 4];
    __shared__ float Bs[BK][BN + 4];

    int tid = threadIdx.x;
    int bm = blockIdx.x * BM;
    int bn = blockIdx.y * BN;
    int ty = tid >> 4;
    int tx = tid & 15;

    int arow = tid >> 2;
    int acol = (tid & 3) * 4;
    int brow = tid >> 4;
    int bcol = (tid & 15) * 4;

    float acc[4][4] = {};

    for (int k0 = 0; k0 < K; k0 += BK) {
        float4 av = make_float4(0.f, 0.f, 0.f, 0.f);
        int gm = bm + arow;
        if (gm < M) av = *(const float4*)(A + (size_t)gm * K + k0 + acol);
        As[acol + 0][arow] = av.x;
        As[acol + 1][arow] = av.y;
        As[acol + 2][arow] = av.z;
        As[acol + 3][arow] = av.w;

        float4 bv = *(const float4*)(W + (size_t)(k0 + brow) * N + bn + bcol);
        *(float4*)&Bs[brow][bcol] = bv;

        __syncthreads();
#pragma unroll
        for (int kk = 0; kk < BK; ++kk) {
            float4 a = *(const float4*)&As[kk][ty * 4];
            float4 b = *(const float4*)&Bs[kk][tx * 4];
            float aa[4] = {a.x, a.y, a.z, a.w};
            float bb[4] = {b.x, b.y, b.z, b.w};
#pragma unroll
            for (int i = 0; i < 4; ++i)
#pragma unroll
                for (int j = 0; j < 4; ++j)
                    acc[i][j] = fmaf(aa[i], bb[j], acc[i][j]);
        }
        __syncthreads();
    }

    float4 bsv = *(const float4*)(bias + bn + tx * 4);
    float bb[4] = {bsv.x, bsv.y, bsv.z, bsv.w};
#pragma unroll
    for (int i = 0; i < 4; ++i) {
        int gm = bm + ty * 4 + i;
        if (gm >= M) break;
        float4 o;
        float* po = (float*)&o;
#pragma unroll
        for (int j = 0; j < 4; ++j) {
            float v = acc[i][j] + bb[j];
            if (RELU) v = fmaxf(v, 0.f);
            po[j] = v;
        }
        *(float4*)(C + (size_t)gm * N + bn + tx * 4) = o;
    }
}

// ---------------------------------------------------------------------------
extern "C" void kernel_launch(void* const* d_in, const int* in_sizes, int n_in,
                              void* d_out, int out_size, void* d_ws, size_t ws_size,
                              hipStream_t stream) {
    const float* x   = (const float*)d_in[0];
    const int*   ei  = (const int*)d_in[1];
    const int*   src = ei;
    const int*   dst = ei + N_EDGES;
    const float* W0a = (const float*)d_in[2];
    const float* b0a = (const float*)d_in[3];
    const float* W0b = (const float*)d_in[4];
    const float* b0b = (const float*)d_in[5];
    const float* W1a = (const float*)d_in[6];
    const float* b1a = (const float*)d_in[7];
    const float* W1b = (const float*)d_in[8];
    const float* b1b = (const float*)d_in[9];
    const float* W2a = (const float*)d_in[10];
    const float* b2a = (const float*)d_in[11];
    const float* W2b = (const float*)d_in[12];
    const float* b2b = (const float*)d_in[13];
    float* out = (float*)d_out;

    const size_t BUF = (size_t)N_NODES * 256 * sizeof(float);  // 10.24 MB
    char* ws = (char*)d_ws;
    float* B0 = (float*)(ws);                    // aggregation output
    float* B1 = (float*)(ws + BUF);              // MLP hidden
    float* B2 = out;                             // layer output lives in d_out
    int* rowptr = (int*)(ws + 2 * BUF);          // 10001 ints
    int* cursor = rowptr + (N_NODES + 1);        // 10000 ints
    int* cnt    = cursor + N_NODES;              // 10000 ints
    int* col    = cnt + N_NODES;                 // 640000 ints

    dim3 gemmGrid((N_NODES + 63) / 64, 256 / 64);
    dim3 gemmBlk(256);
    int edgeBlocks = (N_EDGES + 255) / 256;
    int nodeWaveBlocks = (N_NODES + 3) / 4;  // 4 waves (nodes) per block

    // ---- CSR build (once; edge_index is layer-invariant) ----
    hipMemsetAsync(cnt, 0, N_NODES * sizeof(int), stream);
    hist_kernel<<<edgeBlocks, 256, 0, stream>>>(dst, cnt);
    scan_kernel<<<1, 256, 0, stream>>>(cnt, rowptr, cursor);
    fill_kernel<<<edgeBlocks, 256, 0, stream>>>(src, dst, cursor, col);

    // ---- Layer 0 (C_in = 128) ----
    gather_agg128<<<nodeWaveBlocks, 256, 0, stream>>>(x, rowptr, col, B0);
    gemm_bias<true><<<gemmGrid, gemmBlk, 0, stream>>>(B0, W0a, b0a, B1, N_NODES, 128, 256);
    gemm_bias<true><<<gemmGrid, gemmBlk, 0, stream>>>(B1, W0b, b0b, B2, N_NODES, 256, 256);
    // ---- Layer 1 (C = 256) ----
    gather_agg256<<<nodeWaveBlocks, 256, 0, stream>>>(B2, rowptr, col, B0);
    gemm_bias<true><<<gemmGrid, gemmBlk, 0, stream>>>(B0, W1a, b1a, B1, N_NODES, 256, 256);
    gemm_bias<true><<<gemmGrid, gemmBlk, 0, stream>>>(B1, W1b, b1b, B2, N_NODES, 256, 256);
    // ---- Layer 2 (C = 256, no final ReLU) ----
    gather_agg256<<<nodeWaveBlocks, 256, 0, stream>>>(B2, rowptr, col, B0);
    gemm_bias<true><<<gemmGrid, gemmBlk, 0, stream>>>(B0, W2a, b2a, B1, N_NODES, 256, 256);
    gemm_bias<false><<<gemmGrid, gemmBlk, 0, stream>>>(B1, W2b, b2b, out, N_NODES, 256, 256);
}

// Round 3
// 294.430 us; speedup vs baseline: 18.5526x; 1.4239x over previous
//
#include <hip/hip_runtime.h>

#define N_NODES 10000
#define N_EDGES 640000

typedef short short8 __attribute__((ext_vector_type(8)));
typedef float f32x4 __attribute__((ext_vector_type(4)));

__device__ inline float bf2f(unsigned short u) {
    return __uint_as_float(((unsigned)u) << 16);
}
// round-to-nearest-even f32 -> bf16 (data here is never NaN)
__device__ inline unsigned short f2bf(float f) {
    unsigned u = __float_as_uint(f);
    u += 0x7fffu + ((u >> 16) & 1u);
    return (unsigned short)(u >> 16);
}

// ---------------------------------------------------------------------------
// CSR build: histogram of dst -> single-block scan -> atomic fill
// ---------------------------------------------------------------------------
__global__ __launch_bounds__(256) void hist_kernel(const int* __restrict__ dst,
                                                   int* __restrict__ cnt) {
    int e = blockIdx.x * blockDim.x + threadIdx.x;
    if (e < N_EDGES) atomicAdd(&cnt[dst[e]], 1);
}

__global__ __launch_bounds__(256) void scan_kernel(const int* __restrict__ cnt,
                                                   int* __restrict__ rowptr,
                                                   int* __restrict__ cursor) {
    __shared__ int partial[256];
    const int CH = 40;  // 256*40 >= 10000
    int t = threadIdx.x;
    int beg = t * CH, end = min(beg + CH, N_NODES);
    int s = 0;
    for (int i = beg; i < end; ++i) s += cnt[i];
    partial[t] = s;
    __syncthreads();
    for (int off = 1; off < 256; off <<= 1) {
        int v = partial[t];
        int add = (t >= off) ? partial[t - off] : 0;
        __syncthreads();
        partial[t] = v + add;
        __syncthreads();
    }
    int run = (t == 0) ? 0 : partial[t - 1];
    for (int i = beg; i < end; ++i) {
        rowptr[i] = run;
        cursor[i] = run;
        run += cnt[i];
    }
    if (t == 255) rowptr[N_NODES] = run;
}

__global__ __launch_bounds__(256) void fill_kernel(const int* __restrict__ src,
                                                   const int* __restrict__ dst,
                                                   int* __restrict__ cursor,
                                                   int* __restrict__ col) {
    int e = blockIdx.x * blockDim.x + threadIdx.x;
    if (e < N_EDGES) {
        int pos = atomicAdd(&cursor[dst[e]], 1);
        col[pos] = src[e];
    }
}

// ---------------------------------------------------------------------------
// Conversions: x fp32 -> bf16; weights fp32 [K][N] -> bf16 transposed [N][K]
// ---------------------------------------------------------------------------
__global__ __launch_bounds__(256) void cvt_x_kernel(const float4* __restrict__ x,
                                                    ushort4* __restrict__ xb, int n4) {
    int i = blockIdx.x * 256 + threadIdx.x;
    if (i >= n4) return;
    float4 v = x[i];
    ushort4 o;
    o.x = f2bf(v.x); o.y = f2bf(v.y); o.z = f2bf(v.z); o.w = f2bf(v.w);
    xb[i] = o;
}

struct WList {
    const float* src[6];
    unsigned short* dst[6];
    int K[6];
    int off[7];  // element offsets, N == 256 for all
};

__global__ __launch_bounds__(256) void cvt_w_kernel(WList wl, int total) {
    int idx = blockIdx.x * 256 + threadIdx.x;
    if (idx >= total) return;
    int w = 0;
    while (idx >= wl.off[w + 1]) ++w;
    int r = idx - wl.off[w];
    int k = r >> 8;          // N = 256
    int n = r & 255;
    wl.dst[w][(size_t)n * wl.K[w] + k] = f2bf(wl.src[w][r]);
}

// ---------------------------------------------------------------------------
// Gather aggregation (bf16 in, bf16 out, fp32 accumulate):
//   out[n] = x[n] + sum_{j in row(n)} x[col[j]]
// One wave per node. CPL = bf16 channels per lane (4 -> C=256, 2 -> C=128).
// ---------------------------------------------------------------------------
template <int CPL>
__global__ __launch_bounds__(256) void gather_bf16(const unsigned short* __restrict__ x,
                                                   const int* __restrict__ rowptr,
                                                   const int* __restrict__ col,
                                                   unsigned short* __restrict__ out) {
    int wid = (blockIdx.x * 256 + threadIdx.x) >> 6;
    int lane = threadIdx.x & 63;
    if (wid >= N_NODES) return;
    int beg = rowptr[wid], end = rowptr[wid + 1];

    if (CPL == 4) {
        const ushort4* xr = (const ushort4*)x;  // 64 ushort4 per row
        ushort4 v = xr[(size_t)wid * 64 + lane];
        float a0 = bf2f(v.x), a1 = bf2f(v.y), a2 = bf2f(v.z), a3 = bf2f(v.w);
        int j = beg;
        for (; j + 4 <= end; j += 4) {
            int s0 = col[j], s1 = col[j + 1], s2 = col[j + 2], s3 = col[j + 3];
            ushort4 v0 = xr[(size_t)s0 * 64 + lane];
            ushort4 v1 = xr[(size_t)s1 * 64 + lane];
            ushort4 v2 = xr[(size_t)s2 * 64 + lane];
            ushort4 v3 = xr[(size_t)s3 * 64 + lane];
            a0 += (bf2f(v0.x) + bf2f(v1.x)) + (bf2f(v2.x) + bf2f(v3.x));
            a1 += (bf2f(v0.y) + bf2f(v1.y)) + (bf2f(v2.y) + bf2f(v3.y));
            a2 += (bf2f(v0.z) + bf2f(v1.z)) + (bf2f(v2.z) + bf2f(v3.z));
            a3 += (bf2f(v0.w) + bf2f(v1.w)) + (bf2f(v2.w) + bf2f(v3.w));
        }
        for (; j < end; ++j) {
            ushort4 vv = xr[(size_t)col[j] * 64 + lane];
            a0 += bf2f(vv.x); a1 += bf2f(vv.y); a2 += bf2f(vv.z); a3 += bf2f(vv.w);
        }
        ushort4 o;
        o.x = f2bf(a0); o.y = f2bf(a1); o.z = f2bf(a2); o.w = f2bf(a3);
        ((ushort4*)out)[(size_t)wid * 64 + lane] = o;
    } else {
        const unsigned* xr = (const unsigned*)x;  // 64 uints per row (C=128)
        unsigned v = xr[(size_t)wid * 64 + lane];
        float a0 = bf2f((unsigned short)(v & 0xffff));
        float a1 = bf2f((unsigned short)(v >> 16));
        int j = beg;
        for (; j + 4 <= end; j += 4) {
            int s0 = col[j], s1 = col[j + 1], s2 = col[j + 2], s3 = col[j + 3];
            unsigned v0 = xr[(size_t)s0 * 64 + lane];
            unsigned v1 = xr[(size_t)s1 * 64 + lane];
            unsigned v2 = xr[(size_t)s2 * 64 + lane];
            unsigned v3 = xr[(size_t)s3 * 64 + lane];
            a0 += (bf2f((unsigned short)(v0 & 0xffff)) + bf2f((unsigned short)(v1 & 0xffff))) +
                  (bf2f((unsigned short)(v2 & 0xffff)) + bf2f((unsigned short)(v3 & 0xffff)));
            a1 += (bf2f((unsigned short)(v0 >> 16)) + bf2f((unsigned short)(v1 >> 16))) +
                  (bf2f((unsigned short)(v2 >> 16)) + bf2f((unsigned short)(v3 >> 16)));
        }
        for (; j < end; ++j) {
            unsigned vv = xr[(size_t)col[j] * 64 + lane];
            a0 += bf2f((unsigned short)(vv & 0xffff));
            a1 += bf2f((unsigned short)(vv >> 16));
        }
        unsigned o = (unsigned)f2bf(a0) | ((unsigned)f2bf(a1) << 16);
        ((unsigned*)out)[(size_t)wid * 64 + lane] = o;
    }
}

// ---------------------------------------------------------------------------
// bf16 MFMA GEMM, no LDS. C[M,256] = A[M,K] @ W[K,256] + bias (+ReLU).
// Wt is W transposed: [N=256][K] bf16. One wave (64 thr) per block computes a
// 16x64 output strip (4 n-tiles of 16x16), K fully unrolled in steps of 32.
// Grid: (M/16) * 4 blocks.
// Fragment mapping (mfma_f32_16x16x32_bf16):
//   A: row = lane&15, k = (lane>>4)*8 + j    (j = 0..7)
//   B: col = lane&15, k = (lane>>4)*8 + j
//   D: col = lane&15, row = (lane>>4)*4 + reg
// ---------------------------------------------------------------------------
template <int KSTEPS, bool RELU, bool F32OUT>
__global__ __launch_bounds__(64) void gemm_mfma(const unsigned short* __restrict__ A,
                                                const unsigned short* __restrict__ Wt,
                                                const float* __restrict__ bias,
                                                void* __restrict__ Cout) {
    constexpr int K = KSTEPS * 32;
    int bid = blockIdx.x;
    int rowtile = bid >> 2;
    int nq = bid & 3;
    int r0 = rowtile * 16;
    if (r0 >= N_NODES) return;
    int lane = threadIdx.x;
    int lrow = lane & 15;
    int lkg = lane >> 4;

    const short8* Ap = (const short8*)(A + (size_t)(r0 + lrow) * K + lkg * 8);
    int n0 = nq * 64;
    const short8* Bp = (const short8*)(Wt + (size_t)(n0 + lrow) * K + lkg * 8);
    // offsets in short8 units: k-step = 4; n-tile = 16*K/8 = 2*K
    f32x4 acc[4] = {};

#pragma unroll
    for (int ks = 0; ks < KSTEPS; ++ks) {
        short8 a = Ap[ks * 4];
        short8 b0 = Bp[ks * 4 + 0 * 2 * K];
        short8 b1 = Bp[ks * 4 + 1 * 2 * K];
        short8 b2 = Bp[ks * 4 + 2 * 2 * K];
        short8 b3 = Bp[ks * 4 + 3 * 2 * K];
        acc[0] = __builtin_amdgcn_mfma_f32_16x16x32_bf16(a, b0, acc[0], 0, 0, 0);
        acc[1] = __builtin_amdgcn_mfma_f32_16x16x32_bf16(a, b1, acc[1], 0, 0, 0);
        acc[2] = __builtin_amdgcn_mfma_f32_16x16x32_bf16(a, b2, acc[2], 0, 0, 0);
        acc[3] = __builtin_amdgcn_mfma_f32_16x16x32_bf16(a, b3, acc[3], 0, 0, 0);
    }

    int orow = r0 + lkg * 4;
#pragma unroll
    for (int nt = 0; nt < 4; ++nt) {
        int c = n0 + nt * 16 + lrow;
        float bv = bias[c];
#pragma unroll
        for (int r = 0; r < 4; ++r) {
            float v = acc[nt][r] + bv;
            if (RELU) v = fmaxf(v, 0.f);
            if (F32OUT)
                ((float*)Cout)[(size_t)(orow + r) * 256 + c] = v;
            else
                ((unsigned short*)Cout)[(size_t)(orow + r) * 256 + c] = f2bf(v);
        }
    }
}

// ---------------------------------------------------------------------------
extern "C" void kernel_launch(void* const* d_in, const int* in_sizes, int n_in,
                              void* d_out, int out_size, void* d_ws, size_t ws_size,
                              hipStream_t stream) {
    const float* x   = (const float*)d_in[0];
    const int*   ei  = (const int*)d_in[1];
    const int*   src = ei;
    const int*   dst = ei + N_EDGES;
    const float* W0a = (const float*)d_in[2];
    const float* b0a = (const float*)d_in[3];
    const float* W0b = (const float*)d_in[4];
    const float* b0b = (const float*)d_in[5];
    const float* W1a = (const float*)d_in[6];
    const float* b1a = (const float*)d_in[7];
    const float* W1b = (const float*)d_in[8];
    const float* b1b = (const float*)d_in[9];
    const float* W2a = (const float*)d_in[10];
    const float* b2a = (const float*)d_in[11];
    const float* W2b = (const float*)d_in[12];
    const float* b2b = (const float*)d_in[13];

    char* ws = (char*)d_ws;
    size_t off = 0;
    auto alloc = [&](size_t bytes) {
        void* p = ws + off;
        off += (bytes + 255) & ~(size_t)255;
        return p;
    };
    unsigned short* xb   = (unsigned short*)alloc((size_t)N_NODES * 128 * 2);
    unsigned short* B0   = (unsigned short*)alloc((size_t)N_NODES * 256 * 2);
    unsigned short* B1   = (unsigned short*)alloc((size_t)N_NODES * 256 * 2);
    unsigned short* B2   = (unsigned short*)alloc((size_t)N_NODES * 256 * 2);
    unsigned short* Wt0a = (unsigned short*)alloc(256 * 128 * 2);
    unsigned short* Wt0b = (unsigned short*)alloc(256 * 256 * 2);
    unsigned short* Wt1a = (unsigned short*)alloc(256 * 256 * 2);
    unsigned short* Wt1b = (unsigned short*)alloc(256 * 256 * 2);
    unsigned short* Wt2a = (unsigned short*)alloc(256 * 256 * 2);
    unsigned short* Wt2b = (unsigned short*)alloc(256 * 256 * 2);
    int* rowptr = (int*)alloc((N_NODES + 1) * 4);
    int* cursor = (int*)alloc(N_NODES * 4);
    int* cnt    = (int*)alloc(N_NODES * 4);
    int* col    = (int*)alloc((size_t)N_EDGES * 4);

    int edgeBlocks = (N_EDGES + 255) / 256;       // 2500
    int nodeWaveBlocks = (N_NODES + 3) / 4;       // 2500 (4 waves/block)
    int gemmBlocks = (N_NODES / 16) * 4;          // 2500

    // ---- CSR build ----
    hipMemsetAsync(cnt, 0, N_NODES * sizeof(int), stream);
    hist_kernel<<<edgeBlocks, 256, 0, stream>>>(dst, cnt);
    scan_kernel<<<1, 256, 0, stream>>>(cnt, rowptr, cursor);
    fill_kernel<<<edgeBlocks, 256, 0, stream>>>(src, dst, cursor, col);

    // ---- Precision conversion ----
    cvt_x_kernel<<<(N_NODES * 128 / 4 + 255) / 256, 256, 0, stream>>>(
        (const float4*)x, (ushort4*)xb, N_NODES * 128 / 4);
    WList wl;
    wl.src[0] = W0a; wl.dst[0] = Wt0a; wl.K[0] = 128;
    wl.src[1] = W0b; wl.dst[1] = Wt0b; wl.K[1] = 256;
    wl.src[2] = W1a; wl.dst[2] = Wt1a; wl.K[2] = 256;
    wl.src[3] = W1b; wl.dst[3] = Wt1b; wl.K[3] = 256;
    wl.src[4] = W2a; wl.dst[4] = Wt2a; wl.K[4] = 256;
    wl.src[5] = W2b; wl.dst[5] = Wt2b; wl.K[5] = 256;
    int total = 0;
    for (int i = 0; i < 6; ++i) { wl.off[i] = total; total += wl.K[i] * 256; }
    wl.off[6] = total;
    cvt_w_kernel<<<(total + 255) / 256, 256, 0, stream>>>(wl, total);

    // ---- Layer 0 (C_in = 128) ----
    gather_bf16<2><<<nodeWaveBlocks, 256, 0, stream>>>(xb, rowptr, col, B0);
    gemm_mfma<4, true, false><<<gemmBlocks, 64, 0, stream>>>(B0, Wt0a, b0a, B1);
    gemm_mfma<8, true, false><<<gemmBlocks, 64, 0, stream>>>(B1, Wt0b, b0b, B2);
    // ---- Layer 1 (C = 256) ----
    gather_bf16<4><<<nodeWaveBlocks, 256, 0, stream>>>(B2, rowptr, col, B0);
    gemm_mfma<8, true, false><<<gemmBlocks, 64, 0, stream>>>(B0, Wt1a, b1a, B1);
    gemm_mfma<8, true, false><<<gemmBlocks, 64, 0, stream>>>(B1, Wt1b, b1b, B2);
    // ---- Layer 2 (C = 256, final out fp32, no ReLU) ----
    gather_bf16<4><<<nodeWaveBlocks, 256, 0, stream>>>(B2, rowptr, col, B0);
    gemm_mfma<8, true, false><<<gemmBlocks, 64, 0, stream>>>(B0, Wt2a, b2a, B1);
    gemm_mfma<8, false, true><<<gemmBlocks, 64, 0, stream>>>(B1, Wt2b, b2b, d_out);
}

// Round 4
// 195.106 us; speedup vs baseline: 27.9974x; 1.5091x over previous
//
#include <hip/hip_runtime.h>

#define N_NODES 10000
#define N_EDGES 640000
#define ELL_W   128   // max in-degree capacity; Poisson(64) => P(deg>127) ~ 1e-14

typedef short short8 __attribute__((ext_vector_type(8)));
typedef float f32x4 __attribute__((ext_vector_type(4)));

__device__ inline float bf2f(unsigned short u) {
    return __uint_as_float(((unsigned)u) << 16);
}
// round-to-nearest-even f32 -> bf16 (data here is never NaN)
__device__ inline unsigned short f2bf(float f) {
    unsigned u = __float_as_uint(f);
    u += 0x7fffu + ((u >> 16) & 1u);
    return (unsigned short)(u >> 16);
}

// ---------------------------------------------------------------------------
// ELL build: one atomic pass. ell[d][pos] = (ushort)src, deg[d] = in-degree.
// ---------------------------------------------------------------------------
__global__ __launch_bounds__(256) void fill_ell(const int* __restrict__ src,
                                                const int* __restrict__ dst,
                                                int* __restrict__ deg,
                                                unsigned short* __restrict__ ell) {
    int e = blockIdx.x * 256 + threadIdx.x;
    if (e >= N_EDGES) return;
    int d = dst[e];
    int pos = atomicAdd(&deg[d], 1);
    if (pos < ELL_W) ell[(size_t)d * ELL_W + pos] = (unsigned short)src[e];
}

// ---------------------------------------------------------------------------
// Conversions: x fp32 -> bf16; weights fp32 [K][N] -> bf16 transposed [N][K]
// ---------------------------------------------------------------------------
__global__ __launch_bounds__(256) void cvt_x_kernel(const float4* __restrict__ x,
                                                    ushort4* __restrict__ xb, int n4) {
    int i = blockIdx.x * 256 + threadIdx.x;
    if (i >= n4) return;
    float4 v = x[i];
    ushort4 o;
    o.x = f2bf(v.x); o.y = f2bf(v.y); o.z = f2bf(v.z); o.w = f2bf(v.w);
    xb[i] = o;
}

struct WList {
    const float* src[6];
    unsigned short* dst[6];
    int K[6];
    int off[7];  // element offsets, N == 256 for all
};

__global__ __launch_bounds__(256) void cvt_w_kernel(WList wl, int total) {
    int idx = blockIdx.x * 256 + threadIdx.x;
    if (idx >= total) return;
    int w = 0;
    while (idx >= wl.off[w + 1]) ++w;
    int r = idx - wl.off[w];
    int k = r >> 8;          // N = 256
    int n = r & 255;
    wl.dst[w][(size_t)n * wl.K[w] + k] = f2bf(wl.src[w][r]);
}

// ---------------------------------------------------------------------------
// Gather aggregation (bf16, fp32 accumulate), 128 channels per pass so the
// random-row working set (2.56 MB) stays L2-resident per XCD.
//   out[n][c] = x[n][c] + sum_j x[ell[n][j]][c]
// One wave per (node, half). U2STRIDE = uints per row (C/2). blockIdx.y = half.
// ---------------------------------------------------------------------------
template <int U2STRIDE>
__global__ __launch_bounds__(256) void gather_ell(const unsigned* __restrict__ x,
                                                  const unsigned short* __restrict__ ell,
                                                  const int* __restrict__ deg,
                                                  unsigned* __restrict__ out) {
    int wid = (blockIdx.x * 256 + threadIdx.x) >> 6;  // node id
    int lane = threadIdx.x & 63;
    if (wid >= N_NODES) return;
    int off = blockIdx.y * 64 + lane;  // uint offset within row

    unsigned v = x[(size_t)wid * U2STRIDE + off];
    float a0 = bf2f((unsigned short)(v & 0xffff));
    float a1 = bf2f((unsigned short)(v >> 16));

    int dg = min(deg[wid], ELL_W);
    const unsigned short* row = ell + (size_t)wid * ELL_W;

    int j = 0;
    for (; j + 8 <= dg; j += 8) {
        ushort4 sA = *(const ushort4*)(row + j);
        ushort4 sB = *(const ushort4*)(row + j + 4);
        unsigned v0 = x[(size_t)sA.x * U2STRIDE + off];
        unsigned v1 = x[(size_t)sA.y * U2STRIDE + off];
        unsigned v2 = x[(size_t)sA.z * U2STRIDE + off];
        unsigned v3 = x[(size_t)sA.w * U2STRIDE + off];
        unsigned v4 = x[(size_t)sB.x * U2STRIDE + off];
        unsigned v5 = x[(size_t)sB.y * U2STRIDE + off];
        unsigned v6 = x[(size_t)sB.z * U2STRIDE + off];
        unsigned v7 = x[(size_t)sB.w * U2STRIDE + off];
        a0 += (bf2f((unsigned short)(v0 & 0xffff)) + bf2f((unsigned short)(v1 & 0xffff))) +
              (bf2f((unsigned short)(v2 & 0xffff)) + bf2f((unsigned short)(v3 & 0xffff))) +
              (bf2f((unsigned short)(v4 & 0xffff)) + bf2f((unsigned short)(v5 & 0xffff))) +
              (bf2f((unsigned short)(v6 & 0xffff)) + bf2f((unsigned short)(v7 & 0xffff)));
        a1 += (bf2f((unsigned short)(v0 >> 16)) + bf2f((unsigned short)(v1 >> 16))) +
              (bf2f((unsigned short)(v2 >> 16)) + bf2f((unsigned short)(v3 >> 16))) +
              (bf2f((unsigned short)(v4 >> 16)) + bf2f((unsigned short)(v5 >> 16))) +
              (bf2f((unsigned short)(v6 >> 16)) + bf2f((unsigned short)(v7 >> 16)));
    }
    for (; j < dg; ++j) {
        unsigned vv = x[(size_t)row[j] * U2STRIDE + off];
        a0 += bf2f((unsigned short)(vv & 0xffff));
        a1 += bf2f((unsigned short)(vv >> 16));
    }
    unsigned o = (unsigned)f2bf(a0) | ((unsigned)f2bf(a1) << 16);
    out[(size_t)wid * U2STRIDE + off] = o;
}

// ---------------------------------------------------------------------------
// bf16 MFMA GEMM, no LDS. One wave per block computes a 32x64 output tile
// (2 row-groups x 4 n-tiles of 16x16), K fully unrolled in steps of 32.
// Wt is W transposed: [N=256][K] bf16. Grid: ceil(M/32) * 4 blocks.
// Fragment mapping (mfma_f32_16x16x32_bf16, HW-verified):
//   A: row = lane&15, k = (lane>>4)*8 + j    (j = 0..7)
//   B: col = lane&15, k = (lane>>4)*8 + j
//   D: col = lane&15, row = (lane>>4)*4 + reg
// ---------------------------------------------------------------------------
template <int KSTEPS, bool RELU, bool F32OUT>
__global__ __launch_bounds__(64) void gemm_mfma(const unsigned short* __restrict__ A,
                                                const unsigned short* __restrict__ Wt,
                                                const float* __restrict__ bias,
                                                void* __restrict__ Cout) {
    constexpr int K = KSTEPS * 32;
    int bid = blockIdx.x;
    int rowtile = bid >> 2;
    int nq = bid & 3;
    int r0 = rowtile * 32;
    int lane = threadIdx.x;
    int lrow = lane & 15;
    int lkg = lane >> 4;

    const short8* Ap0 = (const short8*)(A + (size_t)(r0 + lrow) * K + lkg * 8);
    const short8* Ap1 = (const short8*)(A + (size_t)(r0 + 16 + lrow) * K + lkg * 8);
    int n0 = nq * 64;
    const short8* Bp = (const short8*)(Wt + (size_t)(n0 + lrow) * K + lkg * 8);
    // offsets in short8 units: k-step = 4; n-tile stride = 16*K/8 = 2*K
    f32x4 acc[2][4] = {};

#pragma unroll
    for (int ks = 0; ks < KSTEPS; ++ks) {
        short8 a0 = Ap0[ks * 4];
        short8 a1 = Ap1[ks * 4];
        short8 b0 = Bp[ks * 4 + 0 * 2 * K];
        short8 b1 = Bp[ks * 4 + 1 * 2 * K];
        short8 b2 = Bp[ks * 4 + 2 * 2 * K];
        short8 b3 = Bp[ks * 4 + 3 * 2 * K];
        acc[0][0] = __builtin_amdgcn_mfma_f32_16x16x32_bf16(a0, b0, acc[0][0], 0, 0, 0);
        acc[0][1] = __builtin_amdgcn_mfma_f32_16x16x32_bf16(a0, b1, acc[0][1], 0, 0, 0);
        acc[0][2] = __builtin_amdgcn_mfma_f32_16x16x32_bf16(a0, b2, acc[0][2], 0, 0, 0);
        acc[0][3] = __builtin_amdgcn_mfma_f32_16x16x32_bf16(a0, b3, acc[0][3], 0, 0, 0);
        acc[1][0] = __builtin_amdgcn_mfma_f32_16x16x32_bf16(a1, b0, acc[1][0], 0, 0, 0);
        acc[1][1] = __builtin_amdgcn_mfma_f32_16x16x32_bf16(a1, b1, acc[1][1], 0, 0, 0);
        acc[1][2] = __builtin_amdgcn_mfma_f32_16x16x32_bf16(a1, b2, acc[1][2], 0, 0, 0);
        acc[1][3] = __builtin_amdgcn_mfma_f32_16x16x32_bf16(a1, b3, acc[1][3], 0, 0, 0);
    }

#pragma unroll
    for (int rg = 0; rg < 2; ++rg) {
        int orow = r0 + rg * 16 + lkg * 4;
#pragma unroll
        for (int nt = 0; nt < 4; ++nt) {
            int c = n0 + nt * 16 + lrow;
            float bv = bias[c];
#pragma unroll
            for (int r = 0; r < 4; ++r) {
                int grow = orow + r;
                if (grow >= N_NODES) continue;
                float v = acc[rg][nt][r] + bv;
                if (RELU) v = fmaxf(v, 0.f);
                if (F32OUT)
                    ((float*)Cout)[(size_t)grow * 256 + c] = v;
                else
                    ((unsigned short*)Cout)[(size_t)grow * 256 + c] = f2bf(v);
            }
        }
    }
}

// ---------------------------------------------------------------------------
extern "C" void kernel_launch(void* const* d_in, const int* in_sizes, int n_in,
                              void* d_out, int out_size, void* d_ws, size_t ws_size,
                              hipStream_t stream) {
    const float* x   = (const float*)d_in[0];
    const int*   ei  = (const int*)d_in[1];
    const int*   src = ei;
    const int*   dst = ei + N_EDGES;
    const float* W0a = (const float*)d_in[2];
    const float* b0a = (const float*)d_in[3];
    const float* W0b = (const float*)d_in[4];
    const float* b0b = (const float*)d_in[5];
    const float* W1a = (const float*)d_in[6];
    const float* b1a = (const float*)d_in[7];
    const float* W1b = (const float*)d_in[8];
    const float* b1b = (const float*)d_in[9];
    const float* W2a = (const float*)d_in[10];
    const float* b2a = (const float*)d_in[11];
    const float* W2b = (const float*)d_in[12];
    const float* b2b = (const float*)d_in[13];

    char* ws = (char*)d_ws;
    size_t off = 0;
    auto alloc = [&](size_t bytes) {
        void* p = ws + off;
        off += (bytes + 255) & ~(size_t)255;
        return p;
    };
    unsigned short* xb   = (unsigned short*)alloc((size_t)N_NODES * 128 * 2);
    unsigned short* B0   = (unsigned short*)alloc((size_t)N_NODES * 256 * 2);
    unsigned short* B1   = (unsigned short*)alloc((size_t)N_NODES * 256 * 2);
    unsigned short* B2   = (unsigned short*)alloc((size_t)N_NODES * 256 * 2);
    unsigned short* Wt0a = (unsigned short*)alloc(256 * 128 * 2);
    unsigned short* Wt0b = (unsigned short*)alloc(256 * 256 * 2);
    unsigned short* Wt1a = (unsigned short*)alloc(256 * 256 * 2);
    unsigned short* Wt1b = (unsigned short*)alloc(256 * 256 * 2);
    unsigned short* Wt2a = (unsigned short*)alloc(256 * 256 * 2);
    unsigned short* Wt2b = (unsigned short*)alloc(256 * 256 * 2);
    int*            deg  = (int*)alloc(N_NODES * 4);
    unsigned short* ell  = (unsigned short*)alloc((size_t)N_NODES * ELL_W * 2);

    int edgeBlocks = (N_EDGES + 255) / 256;       // 2500
    dim3 gatherGrid1((N_NODES + 3) / 4, 1);       // C=128: one half
    dim3 gatherGrid2((N_NODES + 3) / 4, 2);       // C=256: two halves
    int gemmBlocks = ((N_NODES + 31) / 32) * 4;   // 1252

    // ---- ELL build (one atomic pass; no hist/scan) ----
    hipMemsetAsync(deg, 0, N_NODES * sizeof(int), stream);
    fill_ell<<<edgeBlocks, 256, 0, stream>>>(src, dst, deg, ell);

    // ---- Precision conversion ----
    cvt_x_kernel<<<(N_NODES * 128 / 4 + 255) / 256, 256, 0, stream>>>(
        (const float4*)x, (ushort4*)xb, N_NODES * 128 / 4);
    WList wl;
    wl.src[0] = W0a; wl.dst[0] = Wt0a; wl.K[0] = 128;
    wl.src[1] = W0b; wl.dst[1] = Wt0b; wl.K[1] = 256;
    wl.src[2] = W1a; wl.dst[2] = Wt1a; wl.K[2] = 256;
    wl.src[3] = W1b; wl.dst[3] = Wt1b; wl.K[3] = 256;
    wl.src[4] = W2a; wl.dst[4] = Wt2a; wl.K[4] = 256;
    wl.src[5] = W2b; wl.dst[5] = Wt2b; wl.K[5] = 256;
    int total = 0;
    for (int i = 0; i < 6; ++i) { wl.off[i] = total; total += wl.K[i] * 256; }
    wl.off[6] = total;
    cvt_w_kernel<<<(total + 255) / 256, 256, 0, stream>>>(wl, total);

    // ---- Layer 0 (C_in = 128) ----
    gather_ell<64><<<gatherGrid1, 256, 0, stream>>>((const unsigned*)xb, ell, deg, (unsigned*)B0);
    gemm_mfma<4, true, false><<<gemmBlocks, 64, 0, stream>>>(B0, Wt0a, b0a, B1);
    gemm_mfma<8, true, false><<<gemmBlocks, 64, 0, stream>>>(B1, Wt0b, b0b, B2);
    // ---- Layer 1 (C = 256) ----
    gather_ell<128><<<gatherGrid2, 256, 0, stream>>>((const unsigned*)B2, ell, deg, (unsigned*)B0);
    gemm_mfma<8, true, false><<<gemmBlocks, 64, 0, stream>>>(B0, Wt1a, b1a, B1);
    gemm_mfma<8, true, false><<<gemmBlocks, 64, 0, stream>>>(B1, Wt1b, b1b, B2);
    // ---- Layer 2 (C = 256, final out fp32, no ReLU) ----
    gather_ell<128><<<gatherGrid2, 256, 0, stream>>>((const unsigned*)B2, ell, deg, (unsigned*)B0);
    gemm_mfma<8, true, false><<<gemmBlocks, 64, 0, stream>>>(B0, Wt2a, b2a, B1);
    gemm_mfma<8, false, true><<<gemmBlocks, 64, 0, stream>>>(B1, Wt2b, b2b, d_out);
}